// Round 8
// baseline (173.956 us; speedup 1.0000x reference)
//
#include <hip/hip_runtime.h>

// DiffusionPropagate: out[b,i] = 1 - prod_j (1 - adj[j,i] * p[b,j]), 3 iters.
// B=4, N=4096. Split 3x(stage1+stage2), j-reduction in CHUNKS partials.
// R7 post-mortem: __launch_bounds__(256) without min-waves didn't bound VGPR
// -> occupancy never rose; R5==R7. R8: enforce 16 waves/CU via
// __launch_bounds__(128,4) (VGPR<=128), 2048 blocks. INSTRUMENTED: first
// stage1 replicated x3 via gridDim.z (identical writes, benign) so one
// ~40-100us dispatch surfaces in rocprof top-5 with stage1's real counters.

#define N 4096
#define B 4
#define CHUNKS 256
#define JC (N / CHUNKS)      // 16 j per chunk
#define T1 128               // threads per stage1 block (2 waves)
#define ITILE (T1 * 4)       // 512 output nodes per block
#define IPANELS (N / ITILE)  // 8

__global__ __launch_bounds__(T1, 4) void diffusion_stage1(
    const float* __restrict__ adj,     // [N][N] row-major
    const float* __restrict__ p,       // [B][N]
    float* __restrict__ partial) {     // [CHUNKS][B][N]
    // blockIdx.z = replica index (instrumentation): replicas recompute and
    // store byte-identical values -> benign.
    __shared__ __align__(16) float lds_p[JC][B];

    const int tid = threadIdx.x;
    const int i0  = blockIdx.x * ITILE + tid * 4;
    const int j0  = blockIdx.y * JC;

    if (tid < JC * B) {  // 64 threads load 64 floats, transposed
        int j = tid >> 2, b = tid & 3;
        lds_p[j][b] = p[b * N + j0 + j];
    }
    __syncthreads();

    float4 acc[B];
#pragma unroll
    for (int b = 0; b < B; ++b) acc[b] = make_float4(1.f, 1.f, 1.f, 1.f);

    const float* aptr = adj + (size_t)j0 * N + i0;

#pragma unroll 8
    for (int j = 0; j < JC; ++j) {
        float4 a  = *reinterpret_cast<const float4*>(aptr + (size_t)j * N);
        float4 pv = *reinterpret_cast<const float4*>(&lds_p[j][0]);
        const float pb[4] = {pv.x, pv.y, pv.z, pv.w};
#pragma unroll
        for (int b = 0; b < B; ++b) {
            acc[b].x *= fmaf(-a.x, pb[b], 1.f);
            acc[b].y *= fmaf(-a.y, pb[b], 1.f);
            acc[b].z *= fmaf(-a.z, pb[b], 1.f);
            acc[b].w *= fmaf(-a.w, pb[b], 1.f);
        }
    }

    const int c = blockIdx.y;
#pragma unroll
    for (int b = 0; b < B; ++b) {
        *reinterpret_cast<float4*>(partial + ((size_t)(c * B + b)) * N + i0) = acc[b];
    }
}

__global__ __launch_bounds__(T1) void diffusion_stage2(
    const float* __restrict__ partial,  // [CHUNKS][B][N]
    float* __restrict__ pout) {         // [B][N]
    int t = blockIdx.x * T1 + threadIdx.x;  // 0 .. B*N-1
    int b = t >> 12;        // /N
    int i = t & (N - 1);    // %N
    float prod = 1.f;
#pragma unroll 16
    for (int c = 0; c < CHUNKS; ++c)
        prod *= partial[((size_t)(c * B + b)) * N + i];
    pout[t] = 1.f - prod;
}

// Minimal-scratch fallback (ws confirmed 256 MiB; kept for safety).
__global__ __launch_bounds__(256) void diffusion_full(
    const float* __restrict__ adj, const float* __restrict__ p,
    float* __restrict__ pout) {
    int i = blockIdx.x * 256 + threadIdx.x;
    float acc[B] = {1.f, 1.f, 1.f, 1.f};
    for (int j = 0; j < N; ++j) {
        float a = adj[(size_t)j * N + i];
#pragma unroll
        for (int b = 0; b < B; ++b) acc[b] *= fmaf(-a, p[b * N + j], 1.f);
    }
#pragma unroll
    for (int b = 0; b < B; ++b) pout[b * N + i] = 1.f - acc[b];
}

extern "C" void kernel_launch(void* const* d_in, const int* in_sizes, int n_in,
                              void* d_out, int out_size, void* d_ws, size_t ws_size,
                              hipStream_t stream) {
    const float* preds = (const float*)d_in[0];  // [B][N]
    const float* adj   = (const float*)d_in[1];  // [N][N]
    // d_in[2] = niter (always 3)
    float* out = (float*)d_out;

    float* p0      = (float*)d_ws;               // B*N floats (ping-pong scratch)
    float* partial = p0 + (size_t)B * N;         // CHUNKS*B*N floats (16 MiB)

    const size_t need = ((size_t)B * N + (size_t)CHUNKS * B * N) * sizeof(float);

    if (ws_size >= need) {
        dim3 g1r(IPANELS, CHUNKS, 3);            // instrumented: x3 replicas
        dim3 g1(IPANELS, CHUNKS, 1);             // 8 x 256 = 2048 blocks
        dim3 b1(T1);
        dim3 g2((B * N) / T1), b2(T1);           // 128 blocks x 128 thr
        // iter 1 (replicated stage1 for rocprof visibility): preds -> out
        diffusion_stage1<<<g1r, b1, 0, stream>>>(adj, preds, partial);
        diffusion_stage2<<<g2, b2, 0, stream>>>(partial, out);
        // iter 2: out -> p0
        diffusion_stage1<<<g1, b1, 0, stream>>>(adj, out, partial);
        diffusion_stage2<<<g2, b2, 0, stream>>>(partial, p0);
        // iter 3: p0 -> out
        diffusion_stage1<<<g1, b1, 0, stream>>>(adj, p0, partial);
        diffusion_stage2<<<g2, b2, 0, stream>>>(partial, out);
    } else {
        dim3 g(N / 256), b(256);
        diffusion_full<<<g, b, 0, stream>>>(adj, preds, out);
        diffusion_full<<<g, b, 0, stream>>>(adj, out, p0);
        diffusion_full<<<g, b, 0, stream>>>(adj, p0, out);
    }
}

// Round 9
// 139.945 us; speedup vs baseline: 1.2430x; 1.2430x over previous
//
#include <hip/hip_runtime.h>

// DiffusionPropagate: out[b,i] = 1 - prod_j (1 - adj[j,i] * p[b,j]), 3 iters.
// B=4, N=4096. R8 counters: stage1 VGPR=24 -> compiler register-minimized the
// unrolled loop into ~2-in-flight dependent loads => latency-bound (x3-work
// ran in 1.39x time). R9: explicit 16-deep software pipeline with named
// register array + sched_barrier(0) pins 16 outstanding global_load_dwordx4
// per wave (16 KB/wave in flight; 8 waves/CU => ~128 KB/CU >> ~30 KB needed).
// CHUNKS=128 (JC=32: two 16-deep batches), no min-waves hint.

#define N 4096
#define B 4
#define CHUNKS 128
#define JC (N / CHUNKS)      // 32 j per chunk
#define PF 16                // pipeline depth (outstanding loads per wave)
#define T1 128               // threads per stage1 block (2 waves)
#define ITILE (T1 * 4)       // 512 output nodes per block
#define IPANELS (N / ITILE)  // 8

__global__ __launch_bounds__(T1) void diffusion_stage1(
    const float* __restrict__ adj,     // [N][N] row-major
    const float* __restrict__ p,       // [B][N]
    float* __restrict__ partial) {     // [CHUNKS][B][N]
    __shared__ __align__(16) float lds_p[JC][B];

    const int tid = threadIdx.x;
    const int i0  = blockIdx.x * ITILE + tid * 4;
    const int j0  = blockIdx.y * JC;

    if (tid < JC * B) {  // 128 threads load 128 floats, transposed
        int j = tid >> 2, b = tid & 3;
        lds_p[j][b] = p[b * N + j0 + j];
    }
    __syncthreads();

    float4 acc[B];
#pragma unroll
    for (int b = 0; b < B; ++b) acc[b] = make_float4(1.f, 1.f, 1.f, 1.f);

    const float* aptr = adj + (size_t)j0 * N + i0;

    // ---- 16-deep software pipeline over JC=32 rows ----
    float4 buf[PF];
#pragma unroll
    for (int k = 0; k < PF; ++k)
        buf[k] = *reinterpret_cast<const float4*>(aptr + (size_t)k * N);
    __builtin_amdgcn_sched_barrier(0);   // pin the 16-load batch above

#pragma unroll
    for (int j = 0; j < PF; ++j) {
        float4 a = buf[j];
        buf[j] = *reinterpret_cast<const float4*>(aptr + (size_t)(j + PF) * N);
        float4 pv = *reinterpret_cast<const float4*>(&lds_p[j][0]);
        const float pb[4] = {pv.x, pv.y, pv.z, pv.w};
#pragma unroll
        for (int b = 0; b < B; ++b) {
            acc[b].x *= fmaf(-a.x, pb[b], 1.f);
            acc[b].y *= fmaf(-a.y, pb[b], 1.f);
            acc[b].z *= fmaf(-a.z, pb[b], 1.f);
            acc[b].w *= fmaf(-a.w, pb[b], 1.f);
        }
    }
    __builtin_amdgcn_sched_barrier(0);   // keep batch-2 loads above this point

#pragma unroll
    for (int j = 0; j < PF; ++j) {
        float4 a  = buf[j];
        float4 pv = *reinterpret_cast<const float4*>(&lds_p[j + PF][0]);
        const float pb[4] = {pv.x, pv.y, pv.z, pv.w};
#pragma unroll
        for (int b = 0; b < B; ++b) {
            acc[b].x *= fmaf(-a.x, pb[b], 1.f);
            acc[b].y *= fmaf(-a.y, pb[b], 1.f);
            acc[b].z *= fmaf(-a.z, pb[b], 1.f);
            acc[b].w *= fmaf(-a.w, pb[b], 1.f);
        }
    }

    const int c = blockIdx.y;
#pragma unroll
    for (int b = 0; b < B; ++b) {
        *reinterpret_cast<float4*>(partial + ((size_t)(c * B + b)) * N + i0) = acc[b];
    }
}

__global__ __launch_bounds__(T1) void diffusion_stage2(
    const float* __restrict__ partial,  // [CHUNKS][B][N]
    float* __restrict__ pout) {         // [B][N]
    int t = blockIdx.x * T1 + threadIdx.x;  // 0 .. B*N-1
    int b = t >> 12;        // /N
    int i = t & (N - 1);    // %N
    float prod = 1.f;
#pragma unroll 16
    for (int c = 0; c < CHUNKS; ++c)
        prod *= partial[((size_t)(c * B + b)) * N + i];
    pout[t] = 1.f - prod;
}

// Minimal-scratch fallback (ws confirmed 256 MiB; kept for safety).
__global__ __launch_bounds__(256) void diffusion_full(
    const float* __restrict__ adj, const float* __restrict__ p,
    float* __restrict__ pout) {
    int i = blockIdx.x * 256 + threadIdx.x;
    float acc[B] = {1.f, 1.f, 1.f, 1.f};
    for (int j = 0; j < N; ++j) {
        float a = adj[(size_t)j * N + i];
#pragma unroll
        for (int b = 0; b < B; ++b) acc[b] *= fmaf(-a, p[b * N + j], 1.f);
    }
#pragma unroll
    for (int b = 0; b < B; ++b) pout[b * N + i] = 1.f - acc[b];
}

extern "C" void kernel_launch(void* const* d_in, const int* in_sizes, int n_in,
                              void* d_out, int out_size, void* d_ws, size_t ws_size,
                              hipStream_t stream) {
    const float* preds = (const float*)d_in[0];  // [B][N]
    const float* adj   = (const float*)d_in[1];  // [N][N]
    // d_in[2] = niter (always 3)
    float* out = (float*)d_out;

    float* p0      = (float*)d_ws;               // B*N floats (ping-pong scratch)
    float* partial = p0 + (size_t)B * N;         // CHUNKS*B*N floats (8 MiB)

    const size_t need = ((size_t)B * N + (size_t)CHUNKS * B * N) * sizeof(float);

    if (ws_size >= need) {
        dim3 g1(IPANELS, CHUNKS), b1(T1);        // 8 x 128 = 1024 blocks
        dim3 g2((B * N) / T1), b2(T1);           // 128 blocks
        // iter 1: preds -> out ; iter 2: out -> p0 ; iter 3: p0 -> out
        diffusion_stage1<<<g1, b1, 0, stream>>>(adj, preds, partial);
        diffusion_stage2<<<g2, b2, 0, stream>>>(partial, out);
        diffusion_stage1<<<g1, b1, 0, stream>>>(adj, out, partial);
        diffusion_stage2<<<g2, b2, 0, stream>>>(partial, p0);
        diffusion_stage1<<<g1, b1, 0, stream>>>(adj, p0, partial);
        diffusion_stage2<<<g2, b2, 0, stream>>>(partial, out);
    } else {
        dim3 g(N / 256), b(256);
        diffusion_full<<<g, b, 0, stream>>>(adj, preds, out);
        diffusion_full<<<g, b, 0, stream>>>(adj, out, p0);
        diffusion_full<<<g, b, 0, stream>>>(adj, p0, out);
    }
}